// Round 4
// baseline (267.325 us; speedup 1.0000x reference)
//
#include <hip/hip_runtime.h>

// ---------------------------------------------------------------------------
// EdgeFeatureNet: B=1, N=512. Inputs f32, output f32.
// Layer-1 factorization (see round-3). This round: barrier-free main kernel,
// wave-private hbuf rows, W2/W3 pre-converted to bf16 MFMA B-fragment layout
// in workspace (global, L1/L2-resident), LDS 71.7KB -> 2 blocks/CU.
// ---------------------------------------------------------------------------

using bf16x8 = __attribute__((ext_vector_type(8))) short;
using f32x4  = __attribute__((ext_vector_type(4))) float;

__device__ __forceinline__ unsigned int fbits(float f) {
    unsigned int u; __builtin_memcpy(&u, &f, 4); return u;
}
__device__ __forceinline__ unsigned short f2bf_rne(float f) {
    unsigned int u = fbits(f);
    return (unsigned short)((u + 0x7fffu + ((u >> 16) & 1u)) >> 16);
}
__device__ __forceinline__ unsigned short f2bf_rhu(float f) {  // round-half-up
    return (unsigned short)((fbits(f) + 0x8000u) >> 16);
}

// ---------------------------------------------------------------------------
// Merged pre-pass, 128 threads/block.
//   blocks [0,512): per-node A[i], Bv[i]
//   blocks [512,1535): relpos R[d]
//   blocks [1535,1551): W2/W3 -> bf16 fragment layout
// ---------------------------------------------------------------------------
__global__ void pre_all(const float* __restrict__ nf,
                        const float* __restrict__ Wn2e,
                        const float* __restrict__ bn2e,
                        const float* __restrict__ W1,
                        const float* __restrict__ b1,
                        const float* __restrict__ flow,
                        const float* __restrict__ Wrp,
                        const float* __restrict__ brp,
                        const float* __restrict__ W2,
                        const float* __restrict__ W3,
                        float* __restrict__ A, float* __restrict__ Bv,
                        float* __restrict__ Rm,
                        unsigned short* __restrict__ W2F,
                        unsigned short* __restrict__ W3F)
{
    const int bid = blockIdx.x;
    const int t = threadIdx.x;
    if (bid < 512) {
        __shared__ float nfs[256];
        __shared__ float n2s[128];
        const int i = bid;
        nfs[t]       = nf[i * 256 + t];
        nfs[t + 128] = nf[i * 256 + 128 + t];
        __syncthreads();
        float acc = bn2e[t];
        for (int k = 0; k < 256; k++) acc += nfs[k] * Wn2e[k * 128 + t];
        n2s[t] = acc;
        __syncthreads();
        const float fl = flow[i];
        float aA = b1[t] + fl * W1[428 * 128 + t];
        float aB =         fl * W1[429 * 128 + t];
        for (int k = 0; k < 128; k++) {
            const float s = n2s[k];
            aA += s * W1[k * 128 + t];
            aB += s * W1[(128 + k) * 128 + t];
        }
        A[i * 128 + t]  = aA;
        Bv[i * 128 + t] = aB;
    } else if (bid < 1535) {
        __shared__ float emb[128];
        __shared__ float rp[128];
        const int dix = bid - 512;
        const float d = (float)(dix - 511);
        const int K = t & 63;
        const float denom = powf(2056.0f, (float)K * (1.0f / 64.0f));
        const float ang = d * 3.14159265358979323846f / denom;
        emb[t] = (t < 64) ? sinf(ang) : cosf(ang);
        __syncthreads();
        float acc = brp[t];
        for (int k = 0; k < 128; k++) acc += emb[k] * Wrp[k * 128 + t];
        rp[t] = acc;
        __syncthreads();
        float acc2 = 0.0f;
        for (int k = 0; k < 128; k++) acc2 += rp[k] * W1[(256 + k) * 128 + t];
        Rm[dix * 128 + t] = acc2;
    } else {
        // fragment layout: dst = ((k>>3)*128 + n)*8 + (k&7)
        const int tg = (bid - 1535) * 128 + t;   // 0..2047
        for (int e = 0; e < 8; e++) {
            const int idx = tg + e * 2048;       // 0..16383
            const int k = idx >> 7, n = idx & 127;
            const int dst = ((k >> 3) * 128 + n) * 8 + (k & 7);
            W2F[dst] = f2bf_rne(W2[idx]);
            W3F[dst] = f2bf_rne(W3[idx]);
        }
    }
}

// ---------------------------------------------------------------------------
// Main kernel: grid 1024 (i = bid>>1, j0 = (bid&1)*256), 512 threads (8 waves).
// Wave w owns pairs [32w, 32w+32). NO __syncthreads. LDS 71.7 KB -> 2 blk/CU.
// ---------------------------------------------------------------------------
__global__ __launch_bounds__(512, 4) void edge_main(
    const float* __restrict__ trans,
    const float* __restrict__ sctrans,
    const float* __restrict__ emask,
    const float* __restrict__ W1,
    const float* __restrict__ b2,
    const float* __restrict__ b3,
    const float* __restrict__ lng,
    const float* __restrict__ lnb,
    const float* __restrict__ A,
    const float* __restrict__ Bv,
    const float* __restrict__ Rm,
    const unsigned short* __restrict__ W2F,
    const unsigned short* __restrict__ W3F,
    float* __restrict__ out)
{
    __shared__ __align__(16) short hbuf[256 * 136];  // pitch 136 shorts
    __shared__ int binsD[256];
    __shared__ int binsS[256];

    const int tid = threadIdx.x;
    const int i  = blockIdx.x >> 1;
    const int j0 = (blockIdx.x & 1) << 8;
    const int w = tid >> 6;
    const int l = tid & 63;
    const int q = l >> 4;
    const int ln16 = l & 15;
    const int row0 = 32 * w;

    // ---- per-pair distogram bins, wave-private (lanes 0-31: D, 32-63: S) ----
    {
        const int pl = l & 31;
        const int p = row0 + pl;
        const int j = j0 + p;
        const float* P = (l < 32) ? trans : sctrans;
        const float dx = __fsub_rn(P[i * 3 + 0], P[j * 3 + 0]);
        const float dy = __fsub_rn(P[i * 3 + 1], P[j * 3 + 1]);
        const float dz = __fsub_rn(P[i * 3 + 2], P[j * 3 + 2]);
        const float d2 = __fadd_rn(__fadd_rn(__fmul_rn(dx, dx), __fmul_rn(dy, dy)),
                                   __fmul_rn(dz, dz));
        const double dd = (double)sqrtf(d2);
        int bin = -1;
        if (dd > 20.0) bin = 21;
        else if (dd > 0.001) {
            int b = (int)((dd - 0.001) * (21.0 / 19.999));
            bin = (b > 20) ? 20 : b;
        }
        if (l < 32) binsD[p] = bin; else binsS[p] = bin;
    }

    // ---- h1 assembly (wave-private rows), bf16 pack into hbuf ----
    for (int it = 0; it < 16; it++) {
        const int flat = it * 64 + l;            // 32 pairs x 32 float4
        const int p = row0 + (flat >> 5);
        const int f = (flat & 31) << 2;
        const int j = j0 + p;
        const int didx = i - j + 511;
        const f32x4 bv = *(const f32x4*)&Bv[j * 128 + f];
        const f32x4 r  = *(const f32x4*)&Rm[didx * 128 + f];
        const f32x4 a  = *(const f32x4*)&A[i * 128 + f];
        const int bD = binsD[p], bS = binsS[p];
        const float sD = bD >= 0 ? 1.0f : 0.0f;
        const float sS = bS >= 0 ? 1.0f : 0.0f;
        const int rD = 384 + (bD >= 0 ? bD : 0);
        const int rS = 406 + (bS >= 0 ? bS : 0);
        const f32x4 wd  = *(const f32x4*)&W1[rD * 128 + f];
        const f32x4 wsv = *(const f32x4*)&W1[rS * 128 + f];
        float h0 = a.x + bv.x + r.x + sD * wd.x + sS * wsv.x;
        float h1 = a.y + bv.y + r.y + sD * wd.y + sS * wsv.y;
        float h2 = a.z + bv.z + r.z + sD * wd.z + sS * wsv.z;
        float h3 = a.w + bv.w + r.w + sD * wd.w + sS * wsv.w;
        h0 = fmaxf(h0, 0.0f); h1 = fmaxf(h1, 0.0f);
        h2 = fmaxf(h2, 0.0f); h3 = fmaxf(h3, 0.0f);
        uint2 pk;
        pk.x = ((fbits(h0) + 0x8000u) >> 16) | ((fbits(h1) + 0x8000u) & 0xffff0000u);
        pk.y = ((fbits(h2) + 0x8000u) >> 16) | ((fbits(h3) + 0x8000u) & 0xffff0000u);
        *(uint2*)&hbuf[p * 136 + f] = pk;
    }

    const f32x4 vzero = {0.0f, 0.0f, 0.0f, 0.0f};
    float b2v[8];
    for (int nb = 0; nb < 8; nb++) b2v[nb] = b2[nb * 16 + ln16];

    // ---- layer 2 per 16-pair tile: MFMA + relu/bias + writeback to hbuf ----
    for (int mt = 0; mt < 2; mt++) {
        bf16x8 af[4];
        for (int kb = 0; kb < 4; kb++)
            af[kb] = *(const bf16x8*)&hbuf[(row0 + mt * 16 + ln16) * 136 + q * 8 + kb * 32];
        f32x4 acc[8];
        for (int nb = 0; nb < 8; nb++) acc[nb] = vzero;
        for (int nb = 0; nb < 8; nb++)
            for (int kb = 0; kb < 4; kb++) {
                const bf16x8 bfrg = *(const bf16x8*)&W2F[((kb * 4 + q) * 128 + nb * 16 + ln16) * 8];
                acc[nb] = __builtin_amdgcn_mfma_f32_16x16x32_bf16(af[kb], bfrg, acc[nb], 0, 0, 0);
            }
        for (int nb = 0; nb < 8; nb++)
            for (int rg = 0; rg < 4; rg++) {
                const float v = fmaxf(acc[nb][rg] + b2v[nb], 0.0f);
                hbuf[(row0 + mt * 16 + q * 4 + rg) * 136 + nb * 16 + ln16] = (short)f2bf_rhu(v);
            }
    }

    // ---- layer 3 + LayerNorm + mask + store, per 16-pair tile ----
    float b3v[8], gv[8], bbv[8];
    for (int nb = 0; nb < 8; nb++) {
        const int n = nb * 16 + ln16;
        b3v[nb] = b3[n]; gv[nb] = lng[n]; bbv[nb] = lnb[n];
    }
    for (int mt = 0; mt < 2; mt++) {
        bf16x8 af[4];
        for (int kb = 0; kb < 4; kb++)
            af[kb] = *(const bf16x8*)&hbuf[(row0 + mt * 16 + ln16) * 136 + q * 8 + kb * 32];
        f32x4 acc[8];
        for (int nb = 0; nb < 8; nb++) acc[nb] = vzero;
        for (int nb = 0; nb < 8; nb++)
            for (int kb = 0; kb < 4; kb++) {
                const bf16x8 bfrg = *(const bf16x8*)&W3F[((kb * 4 + q) * 128 + nb * 16 + ln16) * 8];
                acc[nb] = __builtin_amdgcn_mfma_f32_16x16x32_bf16(af[kb], bfrg, acc[nb], 0, 0, 0);
            }
        for (int rg = 0; rg < 4; rg++) {
            float v[8];
            float s = 0.0f;
            for (int nb = 0; nb < 8; nb++) { v[nb] = acc[nb][rg] + b3v[nb]; s += v[nb]; }
            for (int m = 1; m < 16; m <<= 1) s += __shfl_xor(s, m, 64);
            const float mu = s * (1.0f / 128.0f);
            float ss = 0.0f;
            for (int nb = 0; nb < 8; nb++) { const float dv = v[nb] - mu; ss += dv * dv; }
            for (int m = 1; m < 16; m <<= 1) ss += __shfl_xor(ss, m, 64);
            const float rstd = rsqrtf(ss * (1.0f / 128.0f) + 1e-5f);
            const int p = row0 + mt * 16 + q * 4 + rg;
            const int j = j0 + p;
            const float msk = emask[i * 512 + j];
            const int obase = (i * 512 + j) * 128;
            for (int nb = 0; nb < 8; nb++) {
                out[obase + nb * 16 + ln16] = ((v[nb] - mu) * rstd * gv[nb] + bbv[nb]) * msk;
            }
        }
    }
}

// ---------------------------------------------------------------------------
extern "C" void kernel_launch(void* const* d_in, const int* in_sizes, int n_in,
                              void* d_out, int out_size, void* d_ws, size_t ws_size,
                              hipStream_t stream)
{
    const float* nf    = (const float*)d_in[0];
    const float* trans = (const float*)d_in[1];
    const float* sctr  = (const float*)d_in[2];
    const float* emask = (const float*)d_in[3];
    const float* flow  = (const float*)d_in[4];
    const float* Wn2e  = (const float*)d_in[5];
    const float* bn2e  = (const float*)d_in[6];
    const float* Wrp   = (const float*)d_in[7];
    const float* brp   = (const float*)d_in[8];
    const float* W1    = (const float*)d_in[9];
    const float* b1    = (const float*)d_in[10];
    const float* W2    = (const float*)d_in[11];
    const float* b2    = (const float*)d_in[12];
    const float* W3    = (const float*)d_in[13];
    const float* b3    = (const float*)d_in[14];
    const float* lng   = (const float*)d_in[15];
    const float* lnb   = (const float*)d_in[16];

    float* ws = (float*)d_ws;                       // ~1.09 MB used
    float* A  = ws;                                 // [512*128]
    float* Bv = ws + 512 * 128;                     // [512*128]
    float* Rm = ws + 2 * 512 * 128;                 // [1023*128]
    unsigned short* W2F = (unsigned short*)(ws + 2 * 512 * 128 + 1023 * 128);
    unsigned short* W3F = W2F + 16384;
    float* out = (float*)d_out;

    pre_all<<<1551, 128, 0, stream>>>(nf, Wn2e, bn2e, W1, b1, flow, Wrp, brp,
                                      W2, W3, A, Bv, Rm, W2F, W3F);
    edge_main<<<1024, 512, 0, stream>>>(trans, sctr, emask, W1, b2, b3,
                                        lng, lnb, A, Bv, Rm, W2F, W3F, out);
}